// Round 2
// baseline (7435.242 us; speedup 1.0000x reference)
//
#include <hip/hip_runtime.h>
#include <cstdint>

// ---------------------------------------------------------------------------
// 2-layer LSTM encoder, B=32 T=512 F=H=1024.
// Phase 1: pack x, W0, U0, [W1;U1] into bf16 MFMA-fragment order.
// Phase 2: big GEMM xz0 = x @ W0 (bf16, fp32 accum), fragment-packed operands.
// Phase 3: persistent cooperative kernel: 256 WGs, weights in LDS, 513
//          periods covering both layers' recurrences (layer1 lags 1 step).
// ---------------------------------------------------------------------------

typedef __attribute__((ext_vector_type(8))) short bf16x8;
typedef __attribute__((ext_vector_type(4))) float f32x4;

// workspace layout (bytes)
#define XZ0_OFF   0ull                // 16384x4096 bf16   = 134217728
#define XF_OFF    134217728ull        // 16384x1024 bf16   =  33554432
#define W0F_OFF   167772160ull        // 1024x4096  bf16   =   8388608
#define U0F_OFF   176160768ull        // 1024x4096  bf16   =   8388608
#define W1F_OFF   184549376ull        // 2048x4096  bf16   =  16777216
#define H0_OFF    201326592ull        // 2x32x1024  bf16   =    131072
#define H1_OFF    201457664ull        // 2x32x1024  bf16   =    131072
#define FLAG_OFF  201588736ull        // 256x16 u32        =     16384
#define WS_TOTAL  201605120ull

__device__ __forceinline__ float bf2f(short s) {
  unsigned int u = ((unsigned int)(unsigned short)s) << 16;
  return __builtin_bit_cast(float, u);
}
__device__ __forceinline__ short f2bf(float f) {
  unsigned int u = __builtin_bit_cast(unsigned int, f);
  u = (u + 0x7fffu + ((u >> 16) & 1u)) >> 16;   // RTNE
  return (short)u;
}
__device__ __forceinline__ void g2l16(const void* g, void* l) {
  __builtin_amdgcn_global_load_lds(
      (const __attribute__((address_space(1))) unsigned int*)g,
      (__attribute__((address_space(3))) unsigned int*)l, 16, 0, 0);
}
__device__ __forceinline__ float sigm(float x) { return 1.f / (1.f + __expf(-x)); }

// ---------------------------------------------------------------------------
// pack_x: x fp32 [16384][1024] -> bf16 fragments [1024 mtiles][32 ksteps][64][8]
// fragment: lane l holds A[mtile*16 + (l&15)][kstep*32 + (l>>4)*8 + j]
// ---------------------------------------------------------------------------
__global__ __launch_bounds__(256) void pack_x(const float* __restrict__ x,
                                              short* __restrict__ dst) {
  int gid = blockIdx.x * 256 + threadIdx.x;       // 2,097,152 threads
  int lane = gid & 63;
  int unit = gid >> 6;                            // mtile*32 + kstep
  int mtile = unit >> 5, kstep = unit & 31;
  int row = mtile * 16 + (lane & 15);
  int k0 = kstep * 32 + ((lane >> 4) << 3);
  const float* s = x + (size_t)row * 1024 + k0;
  bf16x8 v;
#pragma unroll
  for (int j = 0; j < 8; j++) v[j] = f2bf(s[j]);
  *(bf16x8*)(dst + (size_t)gid * 8) = v;
}

// ---------------------------------------------------------------------------
// pack_w: W fp32 [K][4096] -> bf16 fragments [256 ntiles][K/32][64][8]
// fragment: lane l holds W[kstep*32 + (l>>4)*8 + j][ntile*16 + (l&15)]
// src rows 0..1023 from src0, 1024..2047 from src1 (for stacked [W1;U1]).
// ---------------------------------------------------------------------------
__global__ __launch_bounds__(256) void pack_w(const float* __restrict__ src0,
                                              const float* __restrict__ src1,
                                              int ksh, short* __restrict__ dst) {
  int gid = blockIdx.x * 256 + threadIdx.x;
  int lane = gid & 63;
  int unit = gid >> 6;                            // ntile*ksteps + kstep
  int ntile = unit >> ksh;
  int kstep = unit & ((1 << ksh) - 1);
  int col = ntile * 16 + (lane & 15);
  int k0 = kstep * 32 + ((lane >> 4) << 3);
  const float* s = (k0 < 1024) ? src0 : src1;
  int kk = k0 & 1023;
  bf16x8 v;
#pragma unroll
  for (int j = 0; j < 8; j++) v[j] = f2bf(s[(size_t)(kk + j) * 4096 + col]);
  *(bf16x8*)(dst + (size_t)gid * 8) = v;
}

// ---------------------------------------------------------------------------
// gemm_xw: xz0[16384][4096] = x @ W0  (bf16 in, fp32 accum, bf16 out)
// 128x128 tile, BK=64, 4 waves (2x2), fragment-packed operands, linear LDS,
// global_load_lds width-16, 2-phase double buffer.
// ---------------------------------------------------------------------------
__global__ __launch_bounds__(256) void gemm_xw(const short* __restrict__ xf,
                                               const short* __restrict__ wf,
                                               short* __restrict__ outz) {
  extern __shared__ char smem[];

  int bid = blockIdx.x;                           // 4096 blocks
  int swz = (bid & 7) * 512 + (bid >> 3);         // XCD-aware swizzle
  int bn = swz >> 7;                              // [0,32)
  int bm = swz & 127;                             // [0,128)

  const int tid = threadIdx.x, wid = tid >> 6, lane = tid & 63;
  const int wm = wid >> 1, wn = wid & 1;
  f32x4 acc[4][4] = {};

  const short* xbase = xf + (size_t)(bm * 8) * 32 * 512;  // mtile stride 16384
  const short* wbase = wf + (size_t)(bn * 8) * 32 * 512;

  auto Abuf = [&](int buf) -> short* { return (short*)(smem + buf * 32768); };
  auto Bbuf = [&](int buf) -> short* { return (short*)(smem + 16384 + buf * 32768); };

  auto stage = [&](int buf, int kt) {
    short* A = Abuf(buf);
    short* B = Bbuf(buf);
#pragma unroll
    for (int i = 0; i < 4; i++) {
      int u = wid + 4 * i;                        // 0..15
      int mt = u >> 1, ks = u & 1;
      int gk = kt * 2 + ks;
      g2l16(xbase + (size_t)(mt * 32 + gk) * 512 + lane * 8, A + u * 512);
      g2l16(wbase + (size_t)(mt * 32 + gk) * 512 + lane * 8, B + u * 512);
    }
  };

  stage(0, 0);
  __syncthreads();
  for (int kt = 0; kt < 16; kt++) {
    int buf = kt & 1;
    if (kt < 15) stage(buf ^ 1, kt + 1);
    const short* A = Abuf(buf) + (wm * 4) * 1024;
    const short* B = Bbuf(buf) + (wn * 4) * 1024;
#pragma unroll
    for (int ks = 0; ks < 2; ks++) {
      bf16x8 av[4], bv[4];
#pragma unroll
      for (int i = 0; i < 4; i++) av[i] = *(const bf16x8*)(A + (i * 2 + ks) * 512 + lane * 8);
#pragma unroll
      for (int j = 0; j < 4; j++) bv[j] = *(const bf16x8*)(B + (j * 2 + ks) * 512 + lane * 8);
#pragma unroll
      for (int i = 0; i < 4; i++)
#pragma unroll
        for (int j = 0; j < 4; j++)
          acc[i][j] = __builtin_amdgcn_mfma_f32_16x16x32_bf16(av[i], bv[j], acc[i][j], 0, 0, 0);
    }
    __syncthreads();
  }

  int rb = bm * 128 + wm * 64 + ((lane >> 4) << 2);
  int cb = bn * 128 + wn * 64 + (lane & 15);
#pragma unroll
  for (int i = 0; i < 4; i++)
#pragma unroll
    for (int j = 0; j < 4; j++)
#pragma unroll
      for (int r = 0; r < 4; r++) {
        size_t row = rb + i * 16 + r;
        size_t col = cb + j * 16;
        outz[row * 4096 + col] = f2bf(acc[i][j][r]);
      }
}

// ---------------------------------------------------------------------------
// lstm_persist: 256 WGs x 256 threads, cooperative.
// WG w<128  : layer0, owns hidden units [w*8, w*8+8)      (U0 slice in LDS, 64KB)
// WG w>=128 : layer1, owns hidden units [(w-128)*8, +8)   ([W1;U1] slice, 128KB)
// Period p: layer0 computes step t=p (p<512); layer1 computes t=p-1 (p>=1).
// One flat flag barrier per period (512 barriers total).
// ---------------------------------------------------------------------------
__global__ __launch_bounds__(256, 1) void lstm_persist(
    const short* __restrict__ xz0, const short* __restrict__ u0f,
    const short* __restrict__ w1u1f, const float* __restrict__ b0,
    const float* __restrict__ b1, short* __restrict__ h0buf,
    short* __restrict__ h1buf, unsigned int* __restrict__ flags,
    float* __restrict__ out) {
  extern __shared__ char smem[];
  short* wlds = (short*)smem;                  // weight fragments
  float* red = (float*)(smem + 131072);        // 16KB cross-wave reduce

  const int wg = blockIdx.x;
  const int tid = threadIdx.x;
  const int wid = tid >> 6;
  const int lane = tid & 63;
  const bool l1 = (wg >= 128);
  const int u0 = (wg & 127) * 8;
  const int KS = l1 ? 64 : 32;                 // ksteps (K/32)
  const int ksh = l1 ? 6 : 5;
  const short* wf = l1 ? w1u1f : u0f;

  // ---- LDS fill: gather our 32 gate-columns from natural-ntile fragments ----
  {
    int c = lane & 15;                          // our column within tile
    for (int u = wid; u < 2 * KS; u += 4) {
      int tau = u >> ksh;                       // our tile (0: i|f, 1: g|o)
      int s = u & (KS - 1);                     // kstep
      int gate = tau * 2 + (c >> 3);
      int gc = gate * 1024 + u0 + (c & 7);      // global gate column
      int lanep = (lane & 48) + (gc & 15);      // lane in natural fragment
      const short* src = wf + ((size_t)(((gc >> 4) << ksh) + s) * 64 + lanep) * 8;
      g2l16(src, wlds + (tau * KS + s) * 512);
    }
  }
  __syncthreads();

  // gate-phase thread mapping: one thread per (batch b, unit uu)
  const int b = tid >> 3, uu = tid & 7;
  const int mtg = b >> 4;
  const int lrow = (b >> 2) & 3;
  const int reg = b & 3;
  float bias[4];
  {
    const float* bb = l1 ? b1 : b0;
#pragma unroll
    for (int g = 0; g < 4; g++) bias[g] = bb[g * 1024 + u0 + uu];
  }
  float cst = 0.f;
  const int kbase = wid * (l1 ? 512 : 256);
  const int nhalf = l1 ? 2 : 1;

  for (int p = 0; p <= 512; p++) {
    const bool active = l1 ? (p >= 1) : (p < 512);
    const short* h0r = h0buf + ((p + 1) & 1) * 32768;
    const short* h1r = h1buf + ((p + 1) & 1) * 32768;

    if (active) {
      float xzv[4];
      if (!l1) {
        const short* xp = xz0 + (size_t)(b * 512 + p) * 4096 + u0 + uu;
#pragma unroll
        for (int g = 0; g < 4; g++) xzv[g] = bf2f(xp[g * 1024]);
      } else {
        xzv[0] = xzv[1] = xzv[2] = xzv[3] = 0.f;
      }

      // ---- MFMA: z[32][32] partial over this wave's K slice ----
      f32x4 acc[2][2] = {};
      const short* Abase = l1 ? ((wid < 2) ? h0r : h1r) : h0r;
      const int kloc = l1 ? ((wid & 1) * 512) : kbase;
      for (int half = 0; half < nhalf; half++) {
        bf16x8 a[2][8];
        const int kh = kloc + half * 256;
#pragma unroll
        for (int mt = 0; mt < 2; mt++) {
          const short* ap = Abase + (mt * 16 + (lane & 15)) * 1024 + kh + ((lane >> 4) << 3);
#pragma unroll
          for (int ks = 0; ks < 8; ks++) a[mt][ks] = *(const bf16x8*)(ap + ks * 32);
        }
        const int sgb = (kbase >> 5) + half * 8;
#pragma unroll
        for (int ks = 0; ks < 8; ks++) {
          bf16x8 bt0 = *(const bf16x8*)(wlds + (sgb + ks) * 512 + lane * 8);
          bf16x8 bt1 = *(const bf16x8*)(wlds + (KS + sgb + ks) * 512 + lane * 8);
          acc[0][0] = __builtin_amdgcn_mfma_f32_16x16x32_bf16(a[0][ks], bt0, acc[0][0], 0, 0, 0);
          acc[1][0] = __builtin_amdgcn_mfma_f32_16x16x32_bf16(a[1][ks], bt0, acc[1][0], 0, 0, 0);
          acc[0][1] = __builtin_amdgcn_mfma_f32_16x16x32_bf16(a[0][ks], bt1, acc[0][1], 0, 0, 0);
          acc[1][1] = __builtin_amdgcn_mfma_f32_16x16x32_bf16(a[1][ks], bt1, acc[1][1], 0, 0, 0);
        }
      }
#pragma unroll
      for (int mt = 0; mt < 2; mt++)
#pragma unroll
        for (int tau = 0; tau < 2; tau++)
          *(f32x4*)(red + ((wid * 4 + mt * 2 + tau) * 64 + lane) * 4) = acc[mt][tau];
      __syncthreads();

      // ---- gather z, compute gates, update state ----
      float z[4];
#pragma unroll
      for (int g = 0; g < 4; g++) {
        int tau = g >> 1;
        int lp = lrow * 16 + (g & 1) * 8 + uu;
        float s = bias[g] + xzv[g];
#pragma unroll
        for (int w4 = 0; w4 < 4; w4++)
          s += red[((w4 * 4 + mtg * 2 + tau) * 64 + lp) * 4 + reg];
        z[g] = s;
      }
      float gi = sigm(z[0]);
      float gf = sigm(z[1]);
      float gg = tanhf(z[2]);
      float go = sigm(z[3]);
      cst = gf * cst + gi * gg;
      float hv = go * tanhf(cst);
      short* hw = (l1 ? h1buf : h0buf) + (p & 1) * 32768;
      hw[b * 1024 + u0 + uu] = f2bf(hv);
      if (l1 && p == 512) {
        int oi = b * 1024 + u0 + uu;
        out[oi] = hv;
        out[32768 + oi] = hv;
        out[65536 + oi] = cst;
      }
    }

    // ---- grid barrier (periods 0..511) ----
    if (p < 512) {
      __syncthreads();  // all waves' h stores drained before release
      if (wid == 0) {
        if (lane == 0)
          __hip_atomic_store(&flags[wg * 16], (unsigned int)(p + 1),
                             __ATOMIC_RELEASE, __HIP_MEMORY_SCOPE_AGENT);
        const unsigned int tgt = p + 1;
        unsigned int* fp0 = flags + lane * 64;   // lane covers WGs lane*4..+4
        for (;;) {
          unsigned int m0 = __hip_atomic_load(fp0 + 0,  __ATOMIC_RELAXED, __HIP_MEMORY_SCOPE_AGENT);
          unsigned int m1 = __hip_atomic_load(fp0 + 16, __ATOMIC_RELAXED, __HIP_MEMORY_SCOPE_AGENT);
          unsigned int m2 = __hip_atomic_load(fp0 + 32, __ATOMIC_RELAXED, __HIP_MEMORY_SCOPE_AGENT);
          unsigned int m3 = __hip_atomic_load(fp0 + 48, __ATOMIC_RELAXED, __HIP_MEMORY_SCOPE_AGENT);
          if (__all(m0 >= tgt && m1 >= tgt && m2 >= tgt && m3 >= tgt)) break;
        }
        __builtin_amdgcn_fence(__ATOMIC_ACQUIRE, "agent");
      }
      __syncthreads();
    }
  }
}

// ---------------------------------------------------------------------------
extern "C" void kernel_launch(void* const* d_in, const int* in_sizes, int n_in,
                              void* d_out, int out_size, void* d_ws, size_t ws_size,
                              hipStream_t stream) {
  const float* x  = (const float*)d_in[0];
  const float* W0 = (const float*)d_in[1];
  const float* U0 = (const float*)d_in[2];
  const float* b0 = (const float*)d_in[3];
  const float* W1 = (const float*)d_in[4];
  const float* U1 = (const float*)d_in[5];
  const float* b1 = (const float*)d_in[6];
  char* ws = (char*)d_ws;
  if (ws_size < WS_TOTAL) return;  // loud failure: no output written

  short* xz0p = (short*)(ws + XZ0_OFF);
  short* xfp  = (short*)(ws + XF_OFF);
  short* w0fp = (short*)(ws + W0F_OFF);
  short* u0fp = (short*)(ws + U0F_OFF);
  short* w1fp = (short*)(ws + W1F_OFF);
  short* h0p  = (short*)(ws + H0_OFF);
  short* h1p  = (short*)(ws + H1_OFF);
  unsigned int* flagp = (unsigned int*)(ws + FLAG_OFF);
  float* outp = (float*)d_out;

  (void)hipFuncSetAttribute((const void*)gemm_xw,
      hipFuncAttributeMaxDynamicSharedMemorySize, 65536);
  (void)hipFuncSetAttribute((const void*)lstm_persist,
      hipFuncAttributeMaxDynamicSharedMemorySize, 147456);

  // zero h0/h1 double buffers + barrier flags (contiguous region)
  (void)hipMemsetAsync(ws + H0_OFF, 0, 131072 + 131072 + 16384, stream);

  hipLaunchKernelGGL(pack_x, dim3(8192), dim3(256), 0, stream, x, xfp);
  hipLaunchKernelGGL(pack_w, dim3(2048), dim3(256), 0, stream, W0, W0, 5, w0fp);
  hipLaunchKernelGGL(pack_w, dim3(2048), dim3(256), 0, stream, U0, U0, 5, u0fp);
  hipLaunchKernelGGL(pack_w, dim3(4096), dim3(256), 0, stream, W1, U1, 6, w1fp);
  hipLaunchKernelGGL(gemm_xw, dim3(4096), dim3(256), 65536, stream, xfp, w0fp, xz0p);

  const short* xz0c = xz0p;
  const short* u0fc = u0fp;
  const short* w1fc = w1fp;
  void* kargs[9] = {(void*)&xz0c, (void*)&u0fc, (void*)&w1fc,
                    (void*)&b0,   (void*)&b1,
                    (void*)&h0p,  (void*)&h1p, (void*)&flagp, (void*)&outp};
  (void)hipLaunchCooperativeKernel((const void*)lstm_persist, dim3(256), dim3(256),
                                   kargs, 147456u, stream);
}

// Round 3
// 7004.267 us; speedup vs baseline: 1.0615x; 1.0615x over previous
//
#include <hip/hip_runtime.h>
#include <cstdint>

// ---------------------------------------------------------------------------
// 2-layer LSTM encoder, B=32 T=512 F=H=1024.
// Phase 1: pack x, W0, U0, [W1;U1] into bf16 MFMA-fragment order.
// Phase 2: big GEMM xz0 = x @ W0 (bf16, fp32 accum), fragment-packed operands.
// Phase 3: persistent cooperative kernel: 256 WGs, weights in LDS.
//          Layer0 (WG 0..127) and layer1 (WG 128..255) run DECOUPLED barriers:
//          layer0 writes h0 into an 8-slot ring and may run ahead; layer1
//          consumes h0 slot (q-1) and its own h1 double buffer.
// ---------------------------------------------------------------------------

typedef __attribute__((ext_vector_type(8))) short bf16x8;
typedef __attribute__((ext_vector_type(4))) float f32x4;

// workspace layout (bytes)
#define XZ0_OFF   0ull                // 16384x4096 bf16   = 134217728
#define XF_OFF    134217728ull        // 16384x1024 bf16   =  33554432 (dead after gemm)
#define W0F_OFF   167772160ull        // 1024x4096  bf16   =   8388608
#define U0F_OFF   176160768ull        // 1024x4096  bf16   =   8388608
#define W1F_OFF   184549376ull        // 2048x4096  bf16   =  16777216
#define WS_TOTAL  201326592ull
// overlaid on XF after gemm_xw has consumed it:
#define RING_OFF  XF_OFF              // 8 x 32x1024 bf16  = 524288
#define H1B_OFF   (XF_OFF + 524288ull)   // 2 x 32x1024 bf16 = 131072
#define FLG_OFF   (XF_OFF + 655360ull)   // 256 x 16 u32     = 16384

__device__ __forceinline__ float bf2f(short s) {
  unsigned int u = ((unsigned int)(unsigned short)s) << 16;
  return __builtin_bit_cast(float, u);
}
__device__ __forceinline__ short f2bf(float f) {
  unsigned int u = __builtin_bit_cast(unsigned int, f);
  u = (u + 0x7fffu + ((u >> 16) & 1u)) >> 16;   // RTNE
  return (short)u;
}
__device__ __forceinline__ void g2l16(const void* g, void* l) {
  __builtin_amdgcn_global_load_lds(
      (const __attribute__((address_space(1))) unsigned int*)g,
      (__attribute__((address_space(3))) unsigned int*)l, 16, 0, 0);
}
__device__ __forceinline__ float sigm(float x) { return 1.f / (1.f + __expf(-x)); }

// ---------------------------------------------------------------------------
// pack_x: x fp32 [16384][1024] -> bf16 fragments [1024 mtiles][32 ksteps][64][8]
// ---------------------------------------------------------------------------
__global__ __launch_bounds__(256) void pack_x(const float* __restrict__ x,
                                              short* __restrict__ dst) {
  int gid = blockIdx.x * 256 + threadIdx.x;
  int lane = gid & 63;
  int unit = gid >> 6;
  int mtile = unit >> 5, kstep = unit & 31;
  int row = mtile * 16 + (lane & 15);
  int k0 = kstep * 32 + ((lane >> 4) << 3);
  const float* s = x + (size_t)row * 1024 + k0;
  bf16x8 v;
#pragma unroll
  for (int j = 0; j < 8; j++) v[j] = f2bf(s[j]);
  *(bf16x8*)(dst + (size_t)gid * 8) = v;
}

// ---------------------------------------------------------------------------
// pack_w: W fp32 [K][4096] -> bf16 fragments [256 ntiles][K/32][64][8]
// ---------------------------------------------------------------------------
__global__ __launch_bounds__(256) void pack_w(const float* __restrict__ src0,
                                              const float* __restrict__ src1,
                                              int ksh, short* __restrict__ dst) {
  int gid = blockIdx.x * 256 + threadIdx.x;
  int lane = gid & 63;
  int unit = gid >> 6;
  int ntile = unit >> ksh;
  int kstep = unit & ((1 << ksh) - 1);
  int col = ntile * 16 + (lane & 15);
  int k0 = kstep * 32 + ((lane >> 4) << 3);
  const float* s = (k0 < 1024) ? src0 : src1;
  int kk = k0 & 1023;
  bf16x8 v;
#pragma unroll
  for (int j = 0; j < 8; j++) v[j] = f2bf(s[(size_t)(kk + j) * 4096 + col]);
  *(bf16x8*)(dst + (size_t)gid * 8) = v;
}

// ---------------------------------------------------------------------------
// gemm_xw: xz0[16384][4096] = x @ W0  (bf16 in, fp32 accum, bf16 out)
// ---------------------------------------------------------------------------
__global__ __launch_bounds__(256) void gemm_xw(const short* __restrict__ xf,
                                               const short* __restrict__ wf,
                                               short* __restrict__ outz) {
  extern __shared__ char smem[];

  int bid = blockIdx.x;
  int swz = (bid & 7) * 512 + (bid >> 3);
  int bn = swz >> 7;
  int bm = swz & 127;

  const int tid = threadIdx.x, wid = tid >> 6, lane = tid & 63;
  const int wm = wid >> 1, wn = wid & 1;
  f32x4 acc[4][4] = {};

  const short* xbase = xf + (size_t)(bm * 8) * 32 * 512;
  const short* wbase = wf + (size_t)(bn * 8) * 32 * 512;

  auto Abuf = [&](int buf) -> short* { return (short*)(smem + buf * 32768); };
  auto Bbuf = [&](int buf) -> short* { return (short*)(smem + 16384 + buf * 32768); };

  auto stage = [&](int buf, int kt) {
    short* A = Abuf(buf);
    short* B = Bbuf(buf);
#pragma unroll
    for (int i = 0; i < 4; i++) {
      int u = wid + 4 * i;
      int mt = u >> 1, ks = u & 1;
      int gk = kt * 2 + ks;
      g2l16(xbase + (size_t)(mt * 32 + gk) * 512 + lane * 8, A + u * 512);
      g2l16(wbase + (size_t)(mt * 32 + gk) * 512 + lane * 8, B + u * 512);
    }
  };

  stage(0, 0);
  __syncthreads();
  for (int kt = 0; kt < 16; kt++) {
    int buf = kt & 1;
    if (kt < 15) stage(buf ^ 1, kt + 1);
    const short* A = Abuf(buf) + (wm * 4) * 1024;
    const short* B = Bbuf(buf) + (wn * 4) * 1024;
#pragma unroll
    for (int ks = 0; ks < 2; ks++) {
      bf16x8 av[4], bv[4];
#pragma unroll
      for (int i = 0; i < 4; i++) av[i] = *(const bf16x8*)(A + (i * 2 + ks) * 512 + lane * 8);
#pragma unroll
      for (int j = 0; j < 4; j++) bv[j] = *(const bf16x8*)(B + (j * 2 + ks) * 512 + lane * 8);
#pragma unroll
      for (int i = 0; i < 4; i++)
#pragma unroll
        for (int j = 0; j < 4; j++)
          acc[i][j] = __builtin_amdgcn_mfma_f32_16x16x32_bf16(av[i], bv[j], acc[i][j], 0, 0, 0);
    }
    __syncthreads();
  }

  int rb = bm * 128 + wm * 64 + ((lane >> 4) << 2);
  int cb = bn * 128 + wn * 64 + (lane & 15);
#pragma unroll
  for (int i = 0; i < 4; i++)
#pragma unroll
    for (int j = 0; j < 4; j++)
#pragma unroll
      for (int r = 0; r < 4; r++) {
        size_t row = rb + i * 16 + r;
        size_t col = cb + j * 16;
        outz[row * 4096 + col] = f2bf(acc[i][j][r]);
      }
}

// ---------------------------------------------------------------------------
// lstm_persist
// ---------------------------------------------------------------------------
__global__ __launch_bounds__(256, 1) void lstm_persist(
    const short* __restrict__ xz0, const short* __restrict__ u0f,
    const short* __restrict__ w1u1f, const float* __restrict__ b0,
    const float* __restrict__ b1, short* __restrict__ h0ring,
    short* __restrict__ h1buf, unsigned int* __restrict__ flags,
    float* __restrict__ out) {
  extern __shared__ char smem[];
  short* wlds = (short*)smem;                  // weight fragments (64/128KB)
  float* red = (float*)(smem + 131072);        // 16KB cross-wave reduce

  const int wg = blockIdx.x;
  const int tid = threadIdx.x;
  const int wid = tid >> 6;
  const int lane = tid & 63;
  const bool l1 = (wg >= 128);
  const int u0 = (wg & 127) * 8;
  const int KS = l1 ? 64 : 32;
  const int ksh = l1 ? 6 : 5;
  const short* wf = l1 ? w1u1f : u0f;

  // ---- LDS fill: gather our 32 gate-columns from natural-ntile fragments ----
  {
    int c = lane & 15;
    for (int u = wid; u < 2 * KS; u += 4) {
      int tau = u >> ksh;
      int s = u & (KS - 1);
      int gate = tau * 2 + (c >> 3);
      int gc = gate * 1024 + u0 + (c & 7);
      int lanep = (lane & 48) + (gc & 15);
      const short* src = wf + ((size_t)(((gc >> 4) << ksh) + s) * 64 + lanep) * 8;
      g2l16(src, wlds + (tau * KS + s) * 512);
    }
  }
  __syncthreads();

  const int b = tid >> 3, uu = tid & 7;
  const int mtg = b >> 4, lrow = (b >> 2) & 3, reg = b & 3;
  float bias[4];
  {
    const float* bb = l1 ? b1 : b0;
#pragma unroll
    for (int g = 0; g < 4; g++) bias[g] = bb[g * 1024 + u0 + uu];
  }
  float cst = 0.f;

  unsigned int* ownf = flags + (l1 ? 2048 : 0);
  unsigned int* othf = flags + (l1 ? 0 : 2048);
  unsigned int* myf = ownf + (wg & 127) * 16;

  auto waitfor = [&](unsigned own_t, unsigned oth_t) {
    if (wid == 0) {
      const unsigned int* o0 = ownf + (lane * 2) * 16;
      const unsigned int* o1 = ownf + (lane * 2 + 1) * 16;
      const unsigned int* e0 = othf + (lane * 2) * 16;
      const unsigned int* e1 = othf + (lane * 2 + 1) * 16;
      for (int it = 0; it < (1 << 27); ++it) {
        unsigned a0 = __hip_atomic_load(o0, __ATOMIC_RELAXED, __HIP_MEMORY_SCOPE_AGENT);
        unsigned a1 = __hip_atomic_load(o1, __ATOMIC_RELAXED, __HIP_MEMORY_SCOPE_AGENT);
        unsigned c0 = __hip_atomic_load(e0, __ATOMIC_RELAXED, __HIP_MEMORY_SCOPE_AGENT);
        unsigned c1 = __hip_atomic_load(e1, __ATOMIC_RELAXED, __HIP_MEMORY_SCOPE_AGENT);
        if (__all(a0 >= own_t && a1 >= own_t && c0 >= oth_t && c1 >= oth_t)) break;
      }
      __builtin_amdgcn_fence(__ATOMIC_ACQUIRE, "agent");
    }
    __syncthreads();
  };
  auto release = [&](unsigned v) {
    __syncthreads();   // drain all threads' h stores; also red WAR protection
    if (tid == 0)
      __hip_atomic_store(myf, v, __ATOMIC_RELEASE, __HIP_MEMORY_SCOPE_AGENT);
  };
  auto reduce_gates = [&](f32x4 (&acc)[2][2], const float* xzv, short* hw, bool dump) {
#pragma unroll
    for (int mt = 0; mt < 2; mt++)
#pragma unroll
      for (int tau = 0; tau < 2; tau++)
        *(f32x4*)(red + ((wid * 4 + mt * 2 + tau) * 64 + lane) * 4) = acc[mt][tau];
    __syncthreads();
    float z[4];
#pragma unroll
    for (int g = 0; g < 4; g++) {
      int tau = g >> 1;
      int lp = lrow * 16 + (g & 1) * 8 + uu;
      float s = bias[g] + xzv[g];
#pragma unroll
      for (int w4 = 0; w4 < 4; w4++)
        s += red[((w4 * 4 + mtg * 2 + tau) * 64 + lp) * 4 + reg];
      z[g] = s;
    }
    float gi = sigm(z[0]);
    float gf = sigm(z[1]);
    float gg = tanhf(z[2]);
    float go = sigm(z[3]);
    cst = gf * cst + gi * gg;
    float hv = go * tanhf(cst);
    hw[b * 1024 + u0 + uu] = f2bf(hv);
    if (dump) {
      int oi = b * 1024 + u0 + uu;
      out[oi] = hv;
      out[32768 + oi] = hv;
      out[65536 + oi] = cst;
    }
  };

  if (!l1) {
    // ---------------- layer 0: periods 0..511, h0 ring depth 8 --------------
    const int kbase = wid << 8;     // K-slice base (256 per wave)
    for (int p = 0; p < 512; ++p) {
      // prefetch xz(t=p) before the poll (barrier-independent)
      const unsigned short* xp =
          (const unsigned short*)xz0 + (size_t)(b * 512 + p) * 4096 + u0 + uu;
      unsigned short xr0 = xp[0], xr1 = xp[1024], xr2 = xp[2048], xr3 = xp[3072];
      // own: all l0 done period p-1; oth: l1 consumed ring slot p&7 (lag 7)
      waitfor((unsigned)p, (p >= 8) ? (unsigned)(p - 6) : 0u);
      const short* Ab = h0ring + (size_t)((p - 1) & 7) * 32768;
      const short* ap = Ab + (lane & 15) * 1024 + kbase + ((lane >> 4) << 3);
      bf16x8 a[2][8];
#pragma unroll
      for (int mt = 0; mt < 2; mt++)
#pragma unroll
        for (int ks = 0; ks < 8; ks++)
          a[mt][ks] = *(const bf16x8*)(ap + mt * 16384 + ks * 32);
      __builtin_amdgcn_sched_barrier(0);
      f32x4 acc[2][2] = {};
      const int rb = wid * 8;
#pragma unroll
      for (int ks = 0; ks < 8; ks++) {
        bf16x8 bt0 = *(const bf16x8*)(wlds + (rb + ks) * 512 + lane * 8);
        bf16x8 bt1 = *(const bf16x8*)(wlds + (32 + rb + ks) * 512 + lane * 8);
        acc[0][0] = __builtin_amdgcn_mfma_f32_16x16x32_bf16(a[0][ks], bt0, acc[0][0], 0, 0, 0);
        acc[1][0] = __builtin_amdgcn_mfma_f32_16x16x32_bf16(a[1][ks], bt0, acc[1][0], 0, 0, 0);
        acc[0][1] = __builtin_amdgcn_mfma_f32_16x16x32_bf16(a[0][ks], bt1, acc[0][1], 0, 0, 0);
        acc[1][1] = __builtin_amdgcn_mfma_f32_16x16x32_bf16(a[1][ks], bt1, acc[1][1], 0, 0, 0);
      }
      float xzv[4] = {bf2f((short)xr0), bf2f((short)xr1),
                      bf2f((short)xr2), bf2f((short)xr3)};
      reduce_gates(acc, xzv, h0ring + (size_t)(p & 7) * 32768, false);
      release((unsigned)(p + 1));
    }
  } else {
    // ---------------- layer 1: periods 1..512 (computes t = q-1) ------------
    for (int q = 1; q <= 512; ++q) {
      // own: all l1 done period q-1; oth: l0 done period q-1 (h0 slot q-1 ready)
      waitfor((q >= 2) ? (unsigned)q : 0u, (unsigned)q);
      const short* Ab = (wid < 2) ? (h0ring + (size_t)((q - 1) & 7) * 32768)
                                  : (h1buf + (size_t)(q & 1) * 32768);
      const int kloc = (wid & 1) * 512;
      const short* ap = Ab + (lane & 15) * 1024 + kloc + ((lane >> 4) << 3);
      bf16x8 a[2][2][8];   // [half][mt][ks] -> 128 VGPRs, all in flight
#pragma unroll
      for (int half = 0; half < 2; half++)
#pragma unroll
        for (int mt = 0; mt < 2; mt++)
#pragma unroll
          for (int ks = 0; ks < 8; ks++)
            a[half][mt][ks] = *(const bf16x8*)(ap + half * 256 + mt * 16384 + ks * 32);
      __builtin_amdgcn_sched_barrier(0);
      f32x4 acc[2][2] = {};
#pragma unroll
      for (int half = 0; half < 2; half++) {
        const int rb = wid * 16 + half * 8;
#pragma unroll
        for (int ks = 0; ks < 8; ks++) {
          bf16x8 bt0 = *(const bf16x8*)(wlds + (rb + ks) * 512 + lane * 8);
          bf16x8 bt1 = *(const bf16x8*)(wlds + (64 + rb + ks) * 512 + lane * 8);
          acc[0][0] = __builtin_amdgcn_mfma_f32_16x16x32_bf16(a[half][0][ks], bt0, acc[0][0], 0, 0, 0);
          acc[1][0] = __builtin_amdgcn_mfma_f32_16x16x32_bf16(a[half][1][ks], bt0, acc[1][0], 0, 0, 0);
          acc[0][1] = __builtin_amdgcn_mfma_f32_16x16x32_bf16(a[half][0][ks], bt1, acc[0][1], 0, 0, 0);
          acc[1][1] = __builtin_amdgcn_mfma_f32_16x16x32_bf16(a[half][1][ks], bt1, acc[1][1], 0, 0, 0);
        }
      }
      float xzv[4] = {0.f, 0.f, 0.f, 0.f};
      reduce_gates(acc, xzv, h1buf + (size_t)((q - 1) & 1) * 32768, q == 512);
      release((unsigned)(q + 1));
    }
  }
}

// ---------------------------------------------------------------------------
extern "C" void kernel_launch(void* const* d_in, const int* in_sizes, int n_in,
                              void* d_out, int out_size, void* d_ws, size_t ws_size,
                              hipStream_t stream) {
  const float* x  = (const float*)d_in[0];
  const float* W0 = (const float*)d_in[1];
  const float* U0 = (const float*)d_in[2];
  const float* b0 = (const float*)d_in[3];
  const float* W1 = (const float*)d_in[4];
  const float* U1 = (const float*)d_in[5];
  const float* b1 = (const float*)d_in[6];
  char* ws = (char*)d_ws;
  if (ws_size < WS_TOTAL) return;  // loud failure: no output written

  short* xz0p = (short*)(ws + XZ0_OFF);
  short* xfp  = (short*)(ws + XF_OFF);
  short* w0fp = (short*)(ws + W0F_OFF);
  short* u0fp = (short*)(ws + U0F_OFF);
  short* w1fp = (short*)(ws + W1F_OFF);
  short* ringp = (short*)(ws + RING_OFF);
  short* h1p   = (short*)(ws + H1B_OFF);
  unsigned int* flagp = (unsigned int*)(ws + FLG_OFF);
  float* outp = (float*)d_out;

  (void)hipFuncSetAttribute((const void*)gemm_xw,
      hipFuncAttributeMaxDynamicSharedMemorySize, 65536);
  (void)hipFuncSetAttribute((const void*)lstm_persist,
      hipFuncAttributeMaxDynamicSharedMemorySize, 147456);

  hipLaunchKernelGGL(pack_x, dim3(8192), dim3(256), 0, stream, x, xfp);
  hipLaunchKernelGGL(pack_w, dim3(2048), dim3(256), 0, stream, W0, W0, 5, w0fp);
  hipLaunchKernelGGL(pack_w, dim3(2048), dim3(256), 0, stream, U0, U0, 5, u0fp);
  hipLaunchKernelGGL(pack_w, dim3(4096), dim3(256), 0, stream, W1, U1, 6, w1fp);
  hipLaunchKernelGGL(gemm_xw, dim3(4096), dim3(256), 65536, stream, xfp, w0fp, xz0p);

  // ring/h1/flags overlay the xf region — zero them only after gemm consumed xf
  (void)hipMemsetAsync(ws + RING_OFF, 0, 524288 + 131072 + 16384, stream);

  const short* xz0c = xz0p;
  const short* u0fc = u0fp;
  const short* w1fc = w1fp;
  void* kargs[9] = {(void*)&xz0c, (void*)&u0fc, (void*)&w1fc,
                    (void*)&b0,   (void*)&b1,
                    (void*)&ringp, (void*)&h1p, (void*)&flagp, (void*)&outp};
  (void)hipLaunchCooperativeKernel((const void*)lstm_persist, dim3(256), dim3(256),
                                   kargs, 147456u, stream);
}

// Round 4
// 5190.903 us; speedup vs baseline: 1.4324x; 1.3493x over previous
//
#include <hip/hip_runtime.h>
#include <cstdint>

// ---------------------------------------------------------------------------
// 2-layer LSTM encoder, B=32 T=512 F=H=1024.
// Phase 1: pack x, W0, U0, [W1;U1] into bf16 MFMA-fragment order.
// Phase 2: big GEMM xz0 = x @ W0 (bf16, fp32 accum), fragment-packed operands.
// Phase 3: persistent cooperative kernel: 256 WGs, weights in LDS.
//          ALL cross-WG traffic (h ring, h1, flags) uses agent-scope sc1
//          loads/stores (serviced at LLC, bypass non-coherent per-XCD L2).
//          NO fences -> no per-period buffer_wbl2/buffer_inv.
// ---------------------------------------------------------------------------

typedef __attribute__((ext_vector_type(8))) short bf16x8;
typedef __attribute__((ext_vector_type(4))) float f32x4;
typedef __attribute__((ext_vector_type(2))) unsigned int u32x2;

// workspace layout (bytes)
#define XZ0_OFF   0ull                // 16384x4096 bf16   = 134217728
#define XF_OFF    134217728ull        // 16384x1024 bf16   =  33554432 (dead after gemm)
#define W0F_OFF   167772160ull        // 1024x4096  bf16   =   8388608
#define U0F_OFF   176160768ull        // 1024x4096  bf16   =   8388608
#define W1F_OFF   184549376ull        // 2048x4096  bf16   =  16777216
#define WS_TOTAL  201326592ull
// overlaid on XF after gemm_xw has consumed it:
#define RING_OFF  XF_OFF                 // 8 x 32x1024 bf16 = 524288
#define H1B_OFF   (XF_OFF + 524288ull)   // 2 x 32x1024 bf16 = 131072
#define FLG_OFF   (XF_OFF + 655360ull)   // 256 u32 packed (+pad)

__device__ __forceinline__ float bf2f(short s) {
  unsigned int u = ((unsigned int)(unsigned short)s) << 16;
  return __builtin_bit_cast(float, u);
}
__device__ __forceinline__ short f2bf(float f) {
  unsigned int u = __builtin_bit_cast(unsigned int, f);
  u = (u + 0x7fffu + ((u >> 16) & 1u)) >> 16;   // RTNE
  return (short)u;
}
__device__ __forceinline__ void g2l16(const void* g, void* l) {
  __builtin_amdgcn_global_load_lds(
      (const __attribute__((address_space(1))) unsigned int*)g,
      (__attribute__((address_space(3))) unsigned int*)l, 16, 0, 0);
}
__device__ __forceinline__ float sigm(float x) { return 1.f / (1.f + __expf(-x)); }

// agent-scope (LLC) access helpers — bypass per-XCD L2, no fences needed
__device__ __forceinline__ bf16x8 ld16_sc1(const short* p) {
  bf16x8 r;
  asm volatile("global_load_dwordx4 %0, %1, off sc1" : "=&v"(r) : "v"(p));
  return r;
}
__device__ __forceinline__ void st2_sc1(short* p, unsigned v) {
  asm volatile("global_store_short %0, %1, off sc1" :: "v"(p), "v"(v) : "memory");
}
__device__ __forceinline__ void st4_sc1(unsigned* p, unsigned v) {
  asm volatile("global_store_dword %0, %1, off sc1" :: "v"(p), "v"(v) : "memory");
}
#define VM_DRAIN asm volatile("s_waitcnt vmcnt(0)" ::: "memory")

// ---------------------------------------------------------------------------
// pack_x: x fp32 [16384][1024] -> bf16 fragments [1024 mtiles][32 ksteps][64][8]
// ---------------------------------------------------------------------------
__global__ __launch_bounds__(256) void pack_x(const float* __restrict__ x,
                                              short* __restrict__ dst) {
  int gid = blockIdx.x * 256 + threadIdx.x;
  int lane = gid & 63;
  int unit = gid >> 6;
  int mtile = unit >> 5, kstep = unit & 31;
  int row = mtile * 16 + (lane & 15);
  int k0 = kstep * 32 + ((lane >> 4) << 3);
  const float* s = x + (size_t)row * 1024 + k0;
  bf16x8 v;
#pragma unroll
  for (int j = 0; j < 8; j++) v[j] = f2bf(s[j]);
  *(bf16x8*)(dst + (size_t)gid * 8) = v;
}

// ---------------------------------------------------------------------------
// pack_w: W fp32 [K][4096] -> bf16 fragments [256 ntiles][K/32][64][8]
// ---------------------------------------------------------------------------
__global__ __launch_bounds__(256) void pack_w(const float* __restrict__ src0,
                                              const float* __restrict__ src1,
                                              int ksh, short* __restrict__ dst) {
  int gid = blockIdx.x * 256 + threadIdx.x;
  int lane = gid & 63;
  int unit = gid >> 6;
  int ntile = unit >> ksh;
  int kstep = unit & ((1 << ksh) - 1);
  int col = ntile * 16 + (lane & 15);
  int k0 = kstep * 32 + ((lane >> 4) << 3);
  const float* s = (k0 < 1024) ? src0 : src1;
  int kk = k0 & 1023;
  bf16x8 v;
#pragma unroll
  for (int j = 0; j < 8; j++) v[j] = f2bf(s[(size_t)(kk + j) * 4096 + col]);
  *(bf16x8*)(dst + (size_t)gid * 8) = v;
}

// ---------------------------------------------------------------------------
// gemm_xw: xz0[16384][4096] = x @ W0  (bf16 in, fp32 accum, bf16 out)
// ---------------------------------------------------------------------------
__global__ __launch_bounds__(256) void gemm_xw(const short* __restrict__ xf,
                                               const short* __restrict__ wf,
                                               short* __restrict__ outz) {
  extern __shared__ char smem[];

  int bid = blockIdx.x;
  int swz = (bid & 7) * 512 + (bid >> 3);
  int bn = swz >> 7;
  int bm = swz & 127;

  const int tid = threadIdx.x, wid = tid >> 6, lane = tid & 63;
  const int wm = wid >> 1, wn = wid & 1;
  f32x4 acc[4][4] = {};

  const short* xbase = xf + (size_t)(bm * 8) * 32 * 512;
  const short* wbase = wf + (size_t)(bn * 8) * 32 * 512;

  auto Abuf = [&](int buf) -> short* { return (short*)(smem + buf * 32768); };
  auto Bbuf = [&](int buf) -> short* { return (short*)(smem + 16384 + buf * 32768); };

  auto stage = [&](int buf, int kt) {
    short* A = Abuf(buf);
    short* B = Bbuf(buf);
#pragma unroll
    for (int i = 0; i < 4; i++) {
      int u = wid + 4 * i;
      int mt = u >> 1, ks = u & 1;
      int gk = kt * 2 + ks;
      g2l16(xbase + (size_t)(mt * 32 + gk) * 512 + lane * 8, A + u * 512);
      g2l16(wbase + (size_t)(mt * 32 + gk) * 512 + lane * 8, B + u * 512);
    }
  };

  stage(0, 0);
  __syncthreads();
  for (int kt = 0; kt < 16; kt++) {
    int buf = kt & 1;
    if (kt < 15) stage(buf ^ 1, kt + 1);
    const short* A = Abuf(buf) + (wm * 4) * 1024;
    const short* B = Bbuf(buf) + (wn * 4) * 1024;
#pragma unroll
    for (int ks = 0; ks < 2; ks++) {
      bf16x8 av[4], bv[4];
#pragma unroll
      for (int i = 0; i < 4; i++) av[i] = *(const bf16x8*)(A + (i * 2 + ks) * 512 + lane * 8);
#pragma unroll
      for (int j = 0; j < 4; j++) bv[j] = *(const bf16x8*)(B + (j * 2 + ks) * 512 + lane * 8);
#pragma unroll
      for (int i = 0; i < 4; i++)
#pragma unroll
        for (int j = 0; j < 4; j++)
          acc[i][j] = __builtin_amdgcn_mfma_f32_16x16x32_bf16(av[i], bv[j], acc[i][j], 0, 0, 0);
    }
    __syncthreads();
  }

  int rb = bm * 128 + wm * 64 + ((lane >> 4) << 2);
  int cb = bn * 128 + wn * 64 + (lane & 15);
#pragma unroll
  for (int i = 0; i < 4; i++)
#pragma unroll
    for (int j = 0; j < 4; j++)
#pragma unroll
      for (int r = 0; r < 4; r++) {
        size_t row = rb + i * 16 + r;
        size_t col = cb + j * 16;
        outz[row * 4096 + col] = f2bf(acc[i][j][r]);
      }
}

// ---------------------------------------------------------------------------
// lstm_persist: decoupled flag barriers, all cross-WG data via sc1 @ LLC.
// ---------------------------------------------------------------------------
__global__ __launch_bounds__(256, 1) void lstm_persist(
    const short* __restrict__ xz0, const short* __restrict__ u0f,
    const short* __restrict__ w1u1f, const float* __restrict__ b0,
    const float* __restrict__ b1, short* __restrict__ h0ring,
    short* __restrict__ h1buf, unsigned int* __restrict__ flags,
    float* __restrict__ out) {
  extern __shared__ char smem[];
  short* wlds = (short*)smem;                  // weight fragments (64/128KB)
  float* red = (float*)(smem + 131072);        // 16KB cross-wave reduce

  const int wg = blockIdx.x;
  const int tid = threadIdx.x;
  const int wid = tid >> 6;
  const int lane = tid & 63;
  const bool l1 = (wg >= 128);
  const int u0 = (wg & 127) * 8;
  const int KS = l1 ? 64 : 32;
  const int ksh = l1 ? 6 : 5;
  const short* wf = l1 ? w1u1f : u0f;

  // ---- LDS fill: gather our 32 gate-columns from natural-ntile fragments ----
  {
    int c = lane & 15;
    for (int u = wid; u < 2 * KS; u += 4) {
      int tau = u >> ksh;
      int s = u & (KS - 1);
      int gate = tau * 2 + (c >> 3);
      int gc = gate * 1024 + u0 + (c & 7);
      int lanep = (lane & 48) + (gc & 15);
      const short* src = wf + ((size_t)(((gc >> 4) << ksh) + s) * 64 + lanep) * 8;
      g2l16(src, wlds + (tau * KS + s) * 512);
    }
  }
  __syncthreads();

  const int b = tid >> 3, uu = tid & 7;
  const int mtg = b >> 4, lrow = (b >> 2) & 3, reg = b & 3;
  float bias[4];
  {
    const float* bb = l1 ? b1 : b0;
#pragma unroll
    for (int g = 0; g < 4; g++) bias[g] = bb[g * 1024 + u0 + uu];
  }
  float cst = 0.f;

  // packed flags: [0..127] = layer0 WGs, [128..255] = layer1 WGs
  unsigned int* ownf = flags + (l1 ? 128 : 0);
  unsigned int* othf = flags + (l1 ? 0 : 128);
  unsigned int* myf = ownf + (wg & 127);

  auto waitfor = [&](unsigned own_t, unsigned oth_t) {
    if (wid == 0) {
      const unsigned* po = ownf + lane * 2;
      const unsigned* pe = othf + lane * 2;
      for (int it = 0; it < (1 << 26); ++it) {
        u32x2 ov, ev;
        asm volatile(
            "global_load_dwordx2 %0, %2, off sc1\n\t"
            "global_load_dwordx2 %1, %3, off sc1\n\t"
            "s_waitcnt vmcnt(0)"
            : "=&v"(ov), "=&v"(ev)
            : "v"(po), "v"(pe)
            : "memory");
        if (__all(ov[0] >= own_t && ov[1] >= own_t &&
                  ev[0] >= oth_t && ev[1] >= oth_t)) break;
        asm volatile("s_sleep 1");
      }
    }
    __syncthreads();
  };
  auto release = [&](unsigned v) {
    VM_DRAIN;          // this wave's h stores committed to LLC
    __syncthreads();   // all waves drained (compiler drains vmcnt at barrier)
    if (tid == 0) st4_sc1(myf, v);
  };
  auto reduce_gates = [&](f32x4 (&acc)[2][2], const float* xzv, short* hw, bool dump) {
#pragma unroll
    for (int mt = 0; mt < 2; mt++)
#pragma unroll
      for (int tau = 0; tau < 2; tau++)
        *(f32x4*)(red + ((wid * 4 + mt * 2 + tau) * 64 + lane) * 4) = acc[mt][tau];
    __syncthreads();
    float z[4];
#pragma unroll
    for (int g = 0; g < 4; g++) {
      int tau = g >> 1;
      int lp = lrow * 16 + (g & 1) * 8 + uu;
      float s = bias[g] + xzv[g];
#pragma unroll
      for (int w4 = 0; w4 < 4; w4++)
        s += red[((w4 * 4 + mtg * 2 + tau) * 64 + lp) * 4 + reg];
      z[g] = s;
    }
    float gi = sigm(z[0]);
    float gf = sigm(z[1]);
    float gg = tanhf(z[2]);
    float go = sigm(z[3]);
    cst = gf * cst + gi * gg;
    float hv = go * tanhf(cst);
    st2_sc1(hw + b * 1024 + u0 + uu, (unsigned)(unsigned short)f2bf(hv));
    if (dump) {
      int oi = b * 1024 + u0 + uu;
      out[oi] = hv;
      out[32768 + oi] = hv;
      out[65536 + oi] = cst;
    }
  };

  if (!l1) {
    // ---------------- layer 0: periods 0..511, h0 ring depth 8 --------------
    const int kbase = wid << 8;     // K-slice base (256 per wave)
    for (int p = 0; p < 512; ++p) {
      // prefetch xz(t=p) before the poll (barrier-independent, cached ok)
      const unsigned short* xp =
          (const unsigned short*)xz0 + (size_t)(b * 512 + p) * 4096 + u0 + uu;
      unsigned short xr0 = xp[0], xr1 = xp[1024], xr2 = xp[2048], xr3 = xp[3072];
      // own: all l0 done period p-1; oth: l1 consumed ring slot p&7 (lag 7)
      waitfor((unsigned)p, (p >= 8) ? (unsigned)(p - 6) : 0u);
      const short* ap = h0ring + (size_t)((p - 1) & 7) * 32768 +
                        (lane & 15) * 1024 + kbase + ((lane >> 4) << 3);
      bf16x8 a[2][8];
#pragma unroll
      for (int mt = 0; mt < 2; mt++)
#pragma unroll
        for (int ks = 0; ks < 8; ks++)
          a[mt][ks] = ld16_sc1(ap + mt * 16384 + ks * 32);
      VM_DRAIN;
      __builtin_amdgcn_sched_barrier(0);
      f32x4 acc[2][2] = {};
      const int rb = wid * 8;
#pragma unroll
      for (int ks = 0; ks < 8; ks++) {
        bf16x8 bt0 = *(const bf16x8*)(wlds + (rb + ks) * 512 + lane * 8);
        bf16x8 bt1 = *(const bf16x8*)(wlds + (32 + rb + ks) * 512 + lane * 8);
        acc[0][0] = __builtin_amdgcn_mfma_f32_16x16x32_bf16(a[0][ks], bt0, acc[0][0], 0, 0, 0);
        acc[1][0] = __builtin_amdgcn_mfma_f32_16x16x32_bf16(a[1][ks], bt0, acc[1][0], 0, 0, 0);
        acc[0][1] = __builtin_amdgcn_mfma_f32_16x16x32_bf16(a[0][ks], bt1, acc[0][1], 0, 0, 0);
        acc[1][1] = __builtin_amdgcn_mfma_f32_16x16x32_bf16(a[1][ks], bt1, acc[1][1], 0, 0, 0);
      }
      float xzv[4] = {bf2f((short)xr0), bf2f((short)xr1),
                      bf2f((short)xr2), bf2f((short)xr3)};
      reduce_gates(acc, xzv, h0ring + (size_t)(p & 7) * 32768, false);
      release((unsigned)(p + 1));
    }
  } else {
    // ---------------- layer 1: periods 1..512 (computes t = q-1) ------------
    for (int q = 1; q <= 512; ++q) {
      // own: all l1 done period q-1; oth: l0 done period q-1 (h0 slot q-1 ready)
      waitfor((q >= 2) ? (unsigned)q : 0u, (unsigned)q);
      const short* Ab = (wid < 2) ? (h0ring + (size_t)((q - 1) & 7) * 32768)
                                  : (h1buf + (size_t)(q & 1) * 32768);
      const int kloc = (wid & 1) * 512;
      const short* ap = Ab + (lane & 15) * 1024 + kloc + ((lane >> 4) << 3);
      bf16x8 a[2][2][8];   // [half][mt][ks]
#pragma unroll
      for (int half = 0; half < 2; half++)
#pragma unroll
        for (int mt = 0; mt < 2; mt++)
#pragma unroll
          for (int ks = 0; ks < 8; ks++)
            a[half][mt][ks] = ld16_sc1(ap + half * 256 + mt * 16384 + ks * 32);
      VM_DRAIN;
      __builtin_amdgcn_sched_barrier(0);
      f32x4 acc[2][2] = {};
#pragma unroll
      for (int half = 0; half < 2; half++) {
        const int rb = wid * 16 + half * 8;
#pragma unroll
        for (int ks = 0; ks < 8; ks++) {
          bf16x8 bt0 = *(const bf16x8*)(wlds + (rb + ks) * 512 + lane * 8);
          bf16x8 bt1 = *(const bf16x8*)(wlds + (64 + rb + ks) * 512 + lane * 8);
          acc[0][0] = __builtin_amdgcn_mfma_f32_16x16x32_bf16(a[half][0][ks], bt0, acc[0][0], 0, 0, 0);
          acc[1][0] = __builtin_amdgcn_mfma_f32_16x16x32_bf16(a[half][1][ks], bt0, acc[1][0], 0, 0, 0);
          acc[0][1] = __builtin_amdgcn_mfma_f32_16x16x32_bf16(a[half][0][ks], bt1, acc[0][1], 0, 0, 0);
          acc[1][1] = __builtin_amdgcn_mfma_f32_16x16x32_bf16(a[half][1][ks], bt1, acc[1][1], 0, 0, 0);
        }
      }
      float xzv[4] = {0.f, 0.f, 0.f, 0.f};
      reduce_gates(acc, xzv, h1buf + (size_t)((q - 1) & 1) * 32768, q == 512);
      release((unsigned)(q + 1));
    }
  }
}

// ---------------------------------------------------------------------------
extern "C" void kernel_launch(void* const* d_in, const int* in_sizes, int n_in,
                              void* d_out, int out_size, void* d_ws, size_t ws_size,
                              hipStream_t stream) {
  const float* x  = (const float*)d_in[0];
  const float* W0 = (const float*)d_in[1];
  const float* U0 = (const float*)d_in[2];
  const float* b0 = (const float*)d_in[3];
  const float* W1 = (const float*)d_in[4];
  const float* U1 = (const float*)d_in[5];
  const float* b1 = (const float*)d_in[6];
  char* ws = (char*)d_ws;
  if (ws_size < WS_TOTAL) return;  // loud failure: no output written

  short* xz0p = (short*)(ws + XZ0_OFF);
  short* xfp  = (short*)(ws + XF_OFF);
  short* w0fp = (short*)(ws + W0F_OFF);
  short* u0fp = (short*)(ws + U0F_OFF);
  short* w1fp = (short*)(ws + W1F_OFF);
  short* ringp = (short*)(ws + RING_OFF);
  short* h1p   = (short*)(ws + H1B_OFF);
  unsigned int* flagp = (unsigned int*)(ws + FLG_OFF);
  float* outp = (float*)d_out;

  (void)hipFuncSetAttribute((const void*)gemm_xw,
      hipFuncAttributeMaxDynamicSharedMemorySize, 65536);
  (void)hipFuncSetAttribute((const void*)lstm_persist,
      hipFuncAttributeMaxDynamicSharedMemorySize, 147456);

  hipLaunchKernelGGL(pack_x, dim3(8192), dim3(256), 0, stream, x, xfp);
  hipLaunchKernelGGL(pack_w, dim3(2048), dim3(256), 0, stream, W0, W0, 5, w0fp);
  hipLaunchKernelGGL(pack_w, dim3(2048), dim3(256), 0, stream, U0, U0, 5, u0fp);
  hipLaunchKernelGGL(pack_w, dim3(4096), dim3(256), 0, stream, W1, U1, 6, w1fp);
  hipLaunchKernelGGL(gemm_xw, dim3(4096), dim3(256), 65536, stream, xfp, w0fp, xz0p);

  // ring/h1/flags overlay the xf region — zero them only after gemm consumed xf
  (void)hipMemsetAsync(ws + RING_OFF, 0, 524288 + 131072 + 4096, stream);

  const short* xz0c = xz0p;
  const short* u0fc = u0fp;
  const short* w1fc = w1fp;
  void* kargs[9] = {(void*)&xz0c, (void*)&u0fc, (void*)&w1fc,
                    (void*)&b0,   (void*)&b1,
                    (void*)&ringp, (void*)&h1p, (void*)&flagp, (void*)&outp};
  (void)hipLaunchCooperativeKernel((const void*)lstm_persist, dim3(256), dim3(256),
                                   kargs, 147456u, stream);
}

// Round 5
// 4050.613 us; speedup vs baseline: 1.8356x; 1.2815x over previous
//
#include <hip/hip_runtime.h>
#include <cstdint>

// ---------------------------------------------------------------------------
// 2-layer LSTM encoder, B=32 T=512 F=H=1024.
// Phase 1: pack x, W0, U0, [W1;U1] into bf16 MFMA-fragment order.
// Phase 2: big GEMM xz0 = x @ W0 (bf16, fp32 accum), fragment-packed operands.
// Phase 3: persistent cooperative kernel, 256 WGs, weights in LDS.
//          G=2 batch-group pipelining: batch rows [0,16) and [16,32) are
//          independent recurrence chains with per-group flags; the two chains
//          interleave per WG so each group's LLC hop hides under the other
//          group's compute. All cross-WG data via agent-scope sc1 (LLC).
// ---------------------------------------------------------------------------

typedef __attribute__((ext_vector_type(8))) short bf16x8;
typedef __attribute__((ext_vector_type(4))) float f32x4;
typedef __attribute__((ext_vector_type(2))) unsigned int u32x2;

// workspace layout (bytes)
#define XZ0_OFF   0ull                // 16384x4096 bf16   = 134217728
#define XF_OFF    134217728ull        // 16384x1024 bf16   =  33554432 (dead after gemm)
#define W0F_OFF   167772160ull        // 1024x4096  bf16   =   8388608
#define U0F_OFF   176160768ull        // 1024x4096  bf16   =   8388608
#define W1F_OFF   184549376ull        // 2048x4096  bf16   =  16777216
#define WS_TOTAL  201326592ull
// overlaid on XF after gemm_xw has consumed it:
#define RING_OFF  XF_OFF                 // 8 x 32x1024 bf16 = 524288
#define H1B_OFF   (XF_OFF + 524288ull)   // 2 x 32x1024 bf16 = 131072
#define FLG_OFF   (XF_OFF + 655360ull)   // 512 u32: [l0g0|l0g1|l1g0|l1g1]x128

__device__ __forceinline__ float bf2f(short s) {
  unsigned int u = ((unsigned int)(unsigned short)s) << 16;
  return __builtin_bit_cast(float, u);
}
__device__ __forceinline__ short f2bf(float f) {
  unsigned int u = __builtin_bit_cast(unsigned int, f);
  u = (u + 0x7fffu + ((u >> 16) & 1u)) >> 16;   // RTNE
  return (short)u;
}
__device__ __forceinline__ void g2l16(const void* g, void* l) {
  __builtin_amdgcn_global_load_lds(
      (const __attribute__((address_space(1))) unsigned int*)g,
      (__attribute__((address_space(3))) unsigned int*)l, 16, 0, 0);
}
__device__ __forceinline__ float sigm(float x) { return 1.f / (1.f + __expf(-x)); }

// agent-scope (LLC) access helpers — bypass per-XCD L2 staleness, no fences
__device__ __forceinline__ bf16x8 ld16_sc1(const short* p) {
  bf16x8 r;
  asm volatile("global_load_dwordx4 %0, %1, off sc1" : "=&v"(r) : "v"(p));
  return r;
}
__device__ __forceinline__ void st2_sc1(short* p, unsigned v) {
  asm volatile("global_store_short %0, %1, off sc1" :: "v"(p), "v"(v) : "memory");
}
__device__ __forceinline__ void st4_sc1(unsigned* p, unsigned v) {
  asm volatile("global_store_dword %0, %1, off sc1" :: "v"(p), "v"(v) : "memory");
}
#define VM_DRAIN asm volatile("s_waitcnt vmcnt(0)" ::: "memory")

// ---------------------------------------------------------------------------
// pack_x: x fp32 [16384][1024] -> bf16 fragments [1024 mtiles][32 ksteps][64][8]
// ---------------------------------------------------------------------------
__global__ __launch_bounds__(256) void pack_x(const float* __restrict__ x,
                                              short* __restrict__ dst) {
  int gid = blockIdx.x * 256 + threadIdx.x;
  int lane = gid & 63;
  int unit = gid >> 6;
  int mtile = unit >> 5, kstep = unit & 31;
  int row = mtile * 16 + (lane & 15);
  int k0 = kstep * 32 + ((lane >> 4) << 3);
  const float* s = x + (size_t)row * 1024 + k0;
  bf16x8 v;
#pragma unroll
  for (int j = 0; j < 8; j++) v[j] = f2bf(s[j]);
  *(bf16x8*)(dst + (size_t)gid * 8) = v;
}

// ---------------------------------------------------------------------------
// pack_w: W fp32 [K][4096] -> bf16 fragments [256 ntiles][K/32][64][8]
// ---------------------------------------------------------------------------
__global__ __launch_bounds__(256) void pack_w(const float* __restrict__ src0,
                                              const float* __restrict__ src1,
                                              int ksh, short* __restrict__ dst) {
  int gid = blockIdx.x * 256 + threadIdx.x;
  int lane = gid & 63;
  int unit = gid >> 6;
  int ntile = unit >> ksh;
  int kstep = unit & ((1 << ksh) - 1);
  int col = ntile * 16 + (lane & 15);
  int k0 = kstep * 32 + ((lane >> 4) << 3);
  const float* s = (k0 < 1024) ? src0 : src1;
  int kk = k0 & 1023;
  bf16x8 v;
#pragma unroll
  for (int j = 0; j < 8; j++) v[j] = f2bf(s[(size_t)(kk + j) * 4096 + col]);
  *(bf16x8*)(dst + (size_t)gid * 8) = v;
}

// ---------------------------------------------------------------------------
// gemm_xw: xz0[16384][4096] = x @ W0  (bf16 in, fp32 accum, bf16 out)
// ---------------------------------------------------------------------------
__global__ __launch_bounds__(256) void gemm_xw(const short* __restrict__ xf,
                                               const short* __restrict__ wf,
                                               short* __restrict__ outz) {
  extern __shared__ char smem[];

  int bid = blockIdx.x;
  int swz = (bid & 7) * 512 + (bid >> 3);
  int bn = swz >> 7;
  int bm = swz & 127;

  const int tid = threadIdx.x, wid = tid >> 6, lane = tid & 63;
  const int wm = wid >> 1, wn = wid & 1;
  f32x4 acc[4][4] = {};

  const short* xbase = xf + (size_t)(bm * 8) * 32 * 512;
  const short* wbase = wf + (size_t)(bn * 8) * 32 * 512;

  auto Abuf = [&](int buf) -> short* { return (short*)(smem + buf * 32768); };
  auto Bbuf = [&](int buf) -> short* { return (short*)(smem + 16384 + buf * 32768); };

  auto stage = [&](int buf, int kt) {
    short* A = Abuf(buf);
    short* B = Bbuf(buf);
#pragma unroll
    for (int i = 0; i < 4; i++) {
      int u = wid + 4 * i;
      int mt = u >> 1, ks = u & 1;
      int gk = kt * 2 + ks;
      g2l16(xbase + (size_t)(mt * 32 + gk) * 512 + lane * 8, A + u * 512);
      g2l16(wbase + (size_t)(mt * 32 + gk) * 512 + lane * 8, B + u * 512);
    }
  };

  stage(0, 0);
  __syncthreads();
  for (int kt = 0; kt < 16; kt++) {
    int buf = kt & 1;
    if (kt < 15) stage(buf ^ 1, kt + 1);
    const short* A = Abuf(buf) + (wm * 4) * 1024;
    const short* B = Bbuf(buf) + (wn * 4) * 1024;
#pragma unroll
    for (int ks = 0; ks < 2; ks++) {
      bf16x8 av[4], bv[4];
#pragma unroll
      for (int i = 0; i < 4; i++) av[i] = *(const bf16x8*)(A + (i * 2 + ks) * 512 + lane * 8);
#pragma unroll
      for (int j = 0; j < 4; j++) bv[j] = *(const bf16x8*)(B + (j * 2 + ks) * 512 + lane * 8);
#pragma unroll
      for (int i = 0; i < 4; i++)
#pragma unroll
        for (int j = 0; j < 4; j++)
          acc[i][j] = __builtin_amdgcn_mfma_f32_16x16x32_bf16(av[i], bv[j], acc[i][j], 0, 0, 0);
    }
    __syncthreads();
  }

  int rb = bm * 128 + wm * 64 + ((lane >> 4) << 2);
  int cb = bn * 128 + wn * 64 + (lane & 15);
#pragma unroll
  for (int i = 0; i < 4; i++)
#pragma unroll
    for (int j = 0; j < 4; j++)
#pragma unroll
      for (int r = 0; r < 4; r++) {
        size_t row = rb + i * 16 + r;
        size_t col = cb + j * 16;
        outz[row * 4096 + col] = f2bf(acc[i][j][r]);
      }
}

// ---------------------------------------------------------------------------
// lstm_persist: G=2 batch-group pipelined, per-group flags, sc1 @ LLC.
// flags: [0,128)=l0 g0, [128,256)=l0 g1, [256,384)=l1 g0, [384,512)=l1 g1
// ---------------------------------------------------------------------------
__global__ __launch_bounds__(256, 1) void lstm_persist(
    const short* __restrict__ xz0, const short* __restrict__ u0f,
    const short* __restrict__ w1u1f, const float* __restrict__ b0,
    const float* __restrict__ b1, short* __restrict__ h0ring,
    short* __restrict__ h1buf, unsigned int* __restrict__ flags,
    float* __restrict__ out) {
  extern __shared__ char smem[];
  short* wlds = (short*)smem;                  // weight fragments (64/128KB)
  float* red = (float*)(smem + 131072);        // cross-wave reduce (8KB used)

  const int wg = blockIdx.x;
  const int tid = threadIdx.x;
  const int wid = tid >> 6;
  const int lane = tid & 63;
  const bool l1 = (wg >= 128);
  const int u0 = (wg & 127) * 8;
  const int KS = l1 ? 64 : 32;
  const int ksh = l1 ? 6 : 5;
  const short* wf = l1 ? w1u1f : u0f;

  // ---- LDS fill: gather our 32 gate-columns from natural-ntile fragments ----
  {
    int c = lane & 15;
    for (int u = wid; u < 2 * KS; u += 4) {
      int tau = u >> ksh;
      int s = u & (KS - 1);
      int gate = tau * 2 + (c >> 3);
      int gc = gate * 1024 + u0 + (c & 7);
      int lanep = (lane & 48) + (gc & 15);
      const short* src = wf + ((size_t)(((gc >> 4) << ksh) + s) * 64 + lanep) * 8;
      g2l16(src, wlds + (tau * KS + s) * 512);
    }
  }
  __syncthreads();

  const int bl = (tid & 127) >> 3;          // group-local batch row (gates)
  const int uu = tid & 7;
  const int lrow = bl >> 2, reg = bl & 3;
  float bias[4];
  {
    const float* bb = l1 ? b1 : b0;
#pragma unroll
    for (int g = 0; g < 4; g++) bias[g] = bb[g * 1024 + u0 + uu];
  }

  unsigned int* ownbase = flags + (l1 ? 256 : 0);
  unsigned int* othbase = flags + (l1 ? 0 : 256);

  auto waitfor = [&](int g, unsigned own_t, unsigned oth_t) {
    if ((own_t | oth_t) != 0 && wid == 0) {
      const unsigned* po = ownbase + g * 128 + lane * 2;
      const unsigned* pe = othbase + g * 128 + lane * 2;
      for (int it = 0; it < (1 << 22); ++it) {
        u32x2 ov, ev;
        asm volatile(
            "global_load_dwordx2 %0, %2, off sc1\n\t"
            "global_load_dwordx2 %1, %3, off sc1\n\t"
            "s_waitcnt vmcnt(0)"
            : "=&v"(ov), "=&v"(ev)
            : "v"(po), "v"(pe)
            : "memory");
        if (__all(ov[0] >= own_t && ov[1] >= own_t &&
                  ev[0] >= oth_t && ev[1] >= oth_t)) break;
        asm volatile("s_sleep 1");
      }
    }
    __syncthreads();
  };

  // gather z from red, gates, state update, h store; h-row = g*16+bl
  auto gates = [&](const float* xzv, float& cst, short* hw, bool dump, int g) {
    float z[4];
#pragma unroll
    for (int g4 = 0; g4 < 4; g4++) {
      int tau = g4 >> 1;
      int lp = lrow * 16 + (g4 & 1) * 8 + uu;
      float s = bias[g4] + xzv[g4];
#pragma unroll
      for (int w4 = 0; w4 < 4; w4++)
        s += red[((w4 * 2 + tau) * 64 + lp) * 4 + reg];
      z[g4] = s;
    }
    float gi = sigm(z[0]);
    float gf = sigm(z[1]);
    float gg = tanhf(z[2]);
    float go = sigm(z[3]);
    cst = gf * cst + gi * gg;
    float hv = go * tanhf(cst);
    st2_sc1(hw + (g * 16 + bl) * 1024 + u0 + uu,
            (unsigned)(unsigned short)f2bf(hv));
    if (dump) {
      int oi = (g * 16 + bl) * 1024 + u0 + uu;
      out[oi] = hv;
      out[32768 + oi] = hv;
      out[65536 + oi] = cst;
    }
  };

  auto release = [&](int g, unsigned v) {
    VM_DRAIN;          // own wave's h stores committed
    __syncthreads();   // all waves drained
    if (tid == 0) st4_sc1(ownbase + g * 128 + (wg & 127), v);
  };

  if (!l1) {
    // ------------- layer 0: per group, 512 steps, ring depth 8 -------------
    auto mini0 = [&](const int g, const int t, float& cst) {
      unsigned short xr0 = 0, xr1 = 0, xr2 = 0, xr3 = 0;
      if (tid < 128) {   // prefetch xz(t) before the poll
        const unsigned short* xp = (const unsigned short*)xz0 +
            (size_t)((g * 16 + bl) * 512 + t) * 4096 + u0 + uu;
        xr0 = xp[0]; xr1 = xp[1024]; xr2 = xp[2048]; xr3 = xp[3072];
      }
      waitfor(g, (unsigned)t, (t >= 8) ? (unsigned)(t - 7) : 0u);
      const short* ap = h0ring + (size_t)((t - 1) & 7) * 32768 +
                        (g * 16 + (lane & 15)) * 1024 + (wid << 8) +
                        ((lane >> 4) << 3);
      bf16x8 a[8];
#pragma unroll
      for (int ks = 0; ks < 8; ks++) a[ks] = ld16_sc1(ap + ks * 32);
      VM_DRAIN;
      __builtin_amdgcn_sched_barrier(0);
      f32x4 acc[2] = {};
#pragma unroll
      for (int ks = 0; ks < 8; ks++) {
        bf16x8 bt0 = *(const bf16x8*)(wlds + (wid * 8 + ks) * 512 + lane * 8);
        bf16x8 bt1 = *(const bf16x8*)(wlds + (32 + wid * 8 + ks) * 512 + lane * 8);
        acc[0] = __builtin_amdgcn_mfma_f32_16x16x32_bf16(a[ks], bt0, acc[0], 0, 0, 0);
        acc[1] = __builtin_amdgcn_mfma_f32_16x16x32_bf16(a[ks], bt1, acc[1], 0, 0, 0);
      }
#pragma unroll
      for (int tau = 0; tau < 2; tau++)
        *(f32x4*)(red + ((wid * 2 + tau) * 64 + lane) * 4) = acc[tau];
      __syncthreads();
      if (tid < 128) {
        float xzv[4] = {bf2f((short)xr0), bf2f((short)xr1),
                        bf2f((short)xr2), bf2f((short)xr3)};
        gates(xzv, cst, h0ring + (size_t)(t & 7) * 32768, false, g);
      }
      release(g, (unsigned)(t + 1));
    };
    float c0 = 0.f, c1 = 0.f;
    for (int t = 0; t < 512; ++t) { mini0(0, t, c0); mini0(1, t, c1); }
  } else {
    // ------------- layer 1: per group, 512 steps, h1 double buffer ---------
    auto mini1 = [&](const int g, const int t, float& cst) {
      waitfor(g, (unsigned)t, (unsigned)(t + 1));
      const short* Ab = (wid < 2) ? (h0ring + (size_t)(t & 7) * 32768)
                                  : (h1buf + (size_t)((t - 1) & 1) * 32768);
      const short* ap = Ab + (g * 16 + (lane & 15)) * 1024 + ((wid & 1) << 9) +
                        ((lane >> 4) << 3);
      bf16x8 a[2][8];
#pragma unroll
      for (int half = 0; half < 2; half++)
#pragma unroll
        for (int ks = 0; ks < 8; ks++)
          a[half][ks] = ld16_sc1(ap + half * 256 + ks * 32);
      VM_DRAIN;
      __builtin_amdgcn_sched_barrier(0);
      f32x4 acc[2] = {};
#pragma unroll
      for (int half = 0; half < 2; half++) {
        const int rb = wid * 16 + half * 8;
#pragma unroll
        for (int ks = 0; ks < 8; ks++) {
          bf16x8 bt0 = *(const bf16x8*)(wlds + (rb + ks) * 512 + lane * 8);
          bf16x8 bt1 = *(const bf16x8*)(wlds + (64 + rb + ks) * 512 + lane * 8);
          acc[0] = __builtin_amdgcn_mfma_f32_16x16x32_bf16(a[half][ks], bt0, acc[0], 0, 0, 0);
          acc[1] = __builtin_amdgcn_mfma_f32_16x16x32_bf16(a[half][ks], bt1, acc[1], 0, 0, 0);
        }
      }
#pragma unroll
      for (int tau = 0; tau < 2; tau++)
        *(f32x4*)(red + ((wid * 2 + tau) * 64 + lane) * 4) = acc[tau];
      __syncthreads();
      if (tid < 128) {
        float xzv[4] = {0.f, 0.f, 0.f, 0.f};
        gates(xzv, cst, h1buf + (size_t)(t & 1) * 32768, t == 511, g);
      }
      release(g, (unsigned)(t + 1));
    };
    float c0 = 0.f, c1 = 0.f;
    for (int t = 0; t < 512; ++t) { mini1(0, t, c0); mini1(1, t, c1); }
  }
}

// ---------------------------------------------------------------------------
extern "C" void kernel_launch(void* const* d_in, const int* in_sizes, int n_in,
                              void* d_out, int out_size, void* d_ws, size_t ws_size,
                              hipStream_t stream) {
  const float* x  = (const float*)d_in[0];
  const float* W0 = (const float*)d_in[1];
  const float* U0 = (const float*)d_in[2];
  const float* b0 = (const float*)d_in[3];
  const float* W1 = (const float*)d_in[4];
  const float* U1 = (const float*)d_in[5];
  const float* b1 = (const float*)d_in[6];
  char* ws = (char*)d_ws;
  if (ws_size < WS_TOTAL) return;  // loud failure: no output written

  short* xz0p = (short*)(ws + XZ0_OFF);
  short* xfp  = (short*)(ws + XF_OFF);
  short* w0fp = (short*)(ws + W0F_OFF);
  short* u0fp = (short*)(ws + U0F_OFF);
  short* w1fp = (short*)(ws + W1F_OFF);
  short* ringp = (short*)(ws + RING_OFF);
  short* h1p   = (short*)(ws + H1B_OFF);
  unsigned int* flagp = (unsigned int*)(ws + FLG_OFF);
  float* outp = (float*)d_out;

  (void)hipFuncSetAttribute((const void*)gemm_xw,
      hipFuncAttributeMaxDynamicSharedMemorySize, 65536);
  (void)hipFuncSetAttribute((const void*)lstm_persist,
      hipFuncAttributeMaxDynamicSharedMemorySize, 147456);

  hipLaunchKernelGGL(pack_x, dim3(8192), dim3(256), 0, stream, x, xfp);
  hipLaunchKernelGGL(pack_w, dim3(2048), dim3(256), 0, stream, W0, W0, 5, w0fp);
  hipLaunchKernelGGL(pack_w, dim3(2048), dim3(256), 0, stream, U0, U0, 5, u0fp);
  hipLaunchKernelGGL(pack_w, dim3(4096), dim3(256), 0, stream, W1, U1, 6, w1fp);
  hipLaunchKernelGGL(gemm_xw, dim3(4096), dim3(256), 65536, stream, xfp, w0fp, xz0p);

  // ring/h1/flags overlay the xf region — zero them only after gemm consumed xf
  (void)hipMemsetAsync(ws + RING_OFF, 0, 524288 + 131072 + 4096, stream);

  const short* xz0c = xz0p;
  const short* u0fc = u0fp;
  const short* w1fc = w1fp;
  void* kargs[9] = {(void*)&xz0c, (void*)&u0fc, (void*)&w1fc,
                    (void*)&b0,   (void*)&b1,
                    (void*)&ringp, (void*)&h1p, (void*)&flagp, (void*)&outp};
  (void)hipLaunchCooperativeKernel((const void*)lstm_persist, dim3(256), dim3(256),
                                   kargs, 147456u, stream);
}